// Round 9
// baseline (137.745 us; speedup 1.0000x reference)
//
#include <hip/hip_runtime.h>

#define B_SZ 8
#define T_LEN 4096
#define N_DIM 256
#define H_DIM 512
#define NC 64
#define CL 64
#define ROWS (B_SZ * T_LEN)

typedef __attribute__((ext_vector_type(4))) float f32x4;
typedef __attribute__((ext_vector_type(8))) short bf16x8;

static __device__ __forceinline__ unsigned short f2bf(float f) {
    unsigned int u = __float_as_uint(f);
    unsigned int r = (u + 0x7FFFu + ((u >> 16) & 1u)) >> 16;
    return (unsigned short)r;
}
static __device__ __forceinline__ float bf2f(unsigned short s) {
    return __uint_as_float(((unsigned int)s) << 16);
}

static __device__ __forceinline__ void lam_of(const float* __restrict__ nu,
                                              const float* __restrict__ theta,
                                              int h, float& lre, float& lim) {
    float r = __expf(-__expf(nu[h]));
    float th = theta[h];
    lre = r * __cosf(th);
    lim = r * __sinf(th);
}

// weighted 2-row partial of the CL=64 chunk sum for head h:
//   out = lam^p1 * u1 + lam^(p1+16) * u0,  lam = exp(-e^nu + i*theta)
static __device__ __forceinline__ void csum2(const float* __restrict__ nu,
                                             const float* __restrict__ theta,
                                             int h, int p1,
                                             float ur0, float ui0, float ur1, float ui1,
                                             float& outr, float& outi) {
    const float e  = __expf(nu[h]);
    const float th = theta[h];
    const float fp = (float)p1;
    const float r1 = __expf(-fp * e);
    const float w1r = r1 * __cosf(fp * th);
    const float w1i = r1 * __sinf(fp * th);
    const float r16 = __expf(-16.f * e);
    const float l16r = r16 * __cosf(16.f * th);
    const float l16i = r16 * __sinf(16.f * th);
    float sr = w1r * ur1 - w1i * ui1;
    float si = w1r * ui1 + w1i * ur1;
    const float w0r = w1r * l16r - w1i * l16i;
    const float w0i = w1r * l16i + w1i * l16r;
    sr += w0r * ur0 - w0i * ui0;
    si += w0r * ui0 + w0i * ur0;
    outr = sr; outi = si;
}

// ---------- conversion kernels ----------
__global__ __launch_bounds__(256) void conv_x(const float4* __restrict__ x, ushort4* __restrict__ xb) {
    int id = blockIdx.x * 256 + threadIdx.x;
    float4 v = x[id];
    ushort4 o;
    o.x = f2bf(v.x); o.y = f2bf(v.y); o.z = f2bf(v.z); o.w = f2bf(v.w);
    xb[id] = o;
}

// BT1[n][k] (1024 x 256): n=2h -> Bre[k][h], n=2h+1 -> Bim[k][h]
__global__ __launch_bounds__(256) void conv_Bt(const float* __restrict__ Bre,
                                               const float* __restrict__ Bim,
                                               unsigned short* __restrict__ BT1) {
    int id = blockIdx.x * 256 + threadIdx.x;           // id = k*512 + h
    int k = id >> 9, h = id & 511;
    BT1[(long)(2 * h) * 256 + k]     = f2bf(Bre[id]);
    BT1[(long)(2 * h + 1) * 256 + k] = f2bf(Bim[id]);
}

// CT[n][k] (256 x 1024): k=2h -> Cre[h][n], k=2h+1 -> -Cim[h][n]
__global__ __launch_bounds__(256) void conv_Ct(const float* __restrict__ Cre,
                                               const float* __restrict__ Cim,
                                               unsigned short* __restrict__ CT) {
    int id = blockIdx.x * 256 + threadIdx.x;           // id = h*256 + nn
    int h = id >> 8, nn = id & 255;
    CT[(long)nn * 1024 + 2 * h]     = f2bf(Cre[id]);
    CT[(long)nn * 1024 + 2 * h + 1] = f2bf(-Cim[id]);
}

// ---------- high-occupancy 64x64 MFMA GEMM: out = A(MxK) @ Bt(NxK)^T ----------
// R9: R8's occupancy attack with a RACE-PROOF sync structure.  R8's counted
// vmcnt(N) failed nondeterministically: vmcnt counts ALL VMEM ops in order,
// so compiler-inserted spills / hoisted epilogue loads corrupt the count and
// let waves read half-written LDS.  Fix: minimum 2-phase — 2 buffers, ONE
// __syncthreads() per iteration (its vmcnt(0)+barrier drain is correct
// regardless of stray VMEM), with stage(t+1) issued AFTER the barrier so its
// loads fly under tile t's compute (depth-1 prefetch):
//   stage(0)
//   for t: __syncthreads(); if(t+1<nt) stage(cur^1,t+1); ds_read+MFMA(cur); cur^=1
// The barrier at top of iter t proves (a) tile t's glls landed, (b) buf cur^1
// was consumed last iter -> WAR-safe overwrite.
// LDS = 2x(4+4)KB = 16KB; launch_bounds(256,4) -> ~5 blocks/CU, ~20 waves/CU
// (vs the 19% occupancy plateau of R0-R7).
// Swizzle pair (HW-verified 0 conflicts): write side = pre-permuted global
// k-seg 8*((l&3)^((l>>3)&3)); read side = byte XOR 16*((lane>>4)^((lane>>1)&3)).
// Swapped-operand MFMA (R4-verified): lane holds out row=lane&15,
// cols=(lane>>4)*4+r -> vectorized line-coalesced epilogue.
// MODE 0 (K1): scale by gamma, store bf16 xs, emit fused CL=64 chunk sums.
// MODE 1 (K3): add D[col]*u[row][col], store f32; u from e1b (bf16) if
//              non-null else e1 (f32).
template <int MODE, int KC>
__global__ __launch_bounds__(256, 4) void gemm64(const unsigned short* __restrict__ A,
                                                 const unsigned short* __restrict__ Bt,
                                                 int N,
                                                 const float* __restrict__ e0,
                                                 const float* __restrict__ e1,
                                                 const unsigned short* __restrict__ e1b,
                                                 const float* __restrict__ nu,
                                                 const float* __restrict__ theta,
                                                 float4* __restrict__ sums,
                                                 void* __restrict__ out) {
    __shared__ __align__(16) unsigned short As[2][64 * 32];   // 2 x 4 KB
    __shared__ __align__(16) unsigned short Bs[2][64 * 32];   // 2 x 4 KB
    const int tid = threadIdx.x;
    const int lane = tid & 63;
    const int wave = tid >> 6;
    const int wr = wave >> 1, wc = wave & 1;

    // XCD-aware swizzle (grid % 8 == 0 for both instantiations)
    const int nwg = (int)gridDim.x;
    const int cpx = nwg >> 3;
    const int bid = (int)blockIdx.x;
    const int tile = (bid & 7) * cpx + (bid >> 3);

    const int nTilesN = N >> 6;
    const long tileM = (long)(tile / nTilesN) * 64;
    const long tileN = (long)(tile % nTilesN) * 64;

    // staging: unit == wave covers rows [wave*16,(wave+1)*16); lane -> row
    // wave*16+(lane>>2), 16B slot lane&3; source k-seg pre-swizzled.
    const int sg = 8 * ((lane & 3) ^ ((lane >> 3) & 3));    // ushorts
    const int srow = lane >> 2;
    const unsigned short* Ag = A + (tileM + wave * 16 + srow) * (long)KC + sg;
    const unsigned short* Bg = Bt + (tileN + wave * 16 + srow) * (long)KC + sg;

    auto stage = [&](int buf, int k0) {
        __builtin_amdgcn_global_load_lds(
            (const __attribute__((address_space(1))) unsigned int*)(Ag + k0),
            (__attribute__((address_space(3))) unsigned int*)(As[buf] + wave * 512),
            16, 0, 0);
        __builtin_amdgcn_global_load_lds(
            (const __attribute__((address_space(1))) unsigned int*)(Bg + k0),
            (__attribute__((address_space(3))) unsigned int*)(Bs[buf] + wave * 512),
            16, 0, 0);
    };

    // read-side swizzle (matches write side; row bits 1-2 == lane bits 1-2)
    const int rdA = 16 * ((lane >> 4) ^ ((lane >> 1) & 3));  // byte offset
    const int fr = lane & 15;

    f32x4 acc[2][2] = {};
    const int nt = KC / 32;

    stage(0, 0);

    int cur = 0;
    for (int t = 0; t < nt; ++t) {
        __syncthreads();                 // tile t resident (vmcnt0 drain) + buf cur^1 consumed
        if (t + 1 < nt) stage(cur ^ 1, (t + 1) * 32);

        bf16x8 af[2], bfr[2];
#pragma unroll
        for (int m = 0; m < 2; ++m)
            af[m] = *(const bf16x8*)((const char*)As[cur] + (wr * 32 + m * 16 + fr) * 64 + rdA);
#pragma unroll
        for (int n = 0; n < 2; ++n)
            bfr[n] = *(const bf16x8*)((const char*)Bs[cur] + (wc * 32 + n * 16 + fr) * 64 + rdA);
#pragma unroll
        for (int m = 0; m < 2; ++m)
#pragma unroll
            for (int n = 0; n < 2; ++n)
                acc[m][n] = __builtin_amdgcn_mfma_f32_16x16x32_bf16(bfr[n], af[m], acc[m][n], 0, 0, 0);

        cur ^= 1;
    }

    const int fs = lane >> 4;
    if constexpr (MODE == 0) {
        __syncthreads();                            // all K-loop LDS reads done -> reuse As
        unsigned short* o = (unsigned short*)out;
        float4* red = (float4*)As;                  // 32 float4 = 512 B
        const int p1 = 47 - wr * 32 - fr;           // weight exponent of m=1 row
#pragma unroll
        for (int n = 0; n < 2; ++n) {
            const int col0 = (int)tileN + wc * 32 + n * 16 + fs * 4;   // multiple of 4
            const int h0 = col0 >> 1;
            const float g0 = __expf(e0[h0]);
            const float g1 = __expf(e0[h0 + 1]);
            float ur0[2], ui0[2], ur1[2], ui1[2];
#pragma unroll
            for (int m = 0; m < 2; ++m) {
                const long grow = tileM + wr * 32 + m * 16 + fr;
                const float v0 = acc[m][n][0] * g0;
                const float v1 = acc[m][n][1] * g0;
                const float v2 = acc[m][n][2] * g1;
                const float v3 = acc[m][n][3] * g1;
                ushort4 pk;
                pk.x = f2bf(v0); pk.y = f2bf(v1); pk.z = f2bf(v2); pk.w = f2bf(v3);
                *(ushort4*)(o + grow * N + col0) = pk;                 // 8B line-coalesced
                ur0[m] = v0; ui0[m] = v1; ur1[m] = v2; ui1[m] = v3;
            }
            float sr0, si0, sr1, si1;
            csum2(nu, theta, h0,     p1, ur0[0], ui0[0], ur0[1], ui0[1], sr0, si0);
            csum2(nu, theta, h0 + 1, p1, ur1[0], ui1[0], ur1[1], ui1[1], sr1, si1);
#pragma unroll
            for (int st = 1; st < 16; st <<= 1) {
                sr0 += __shfl_xor(sr0, st);
                si0 += __shfl_xor(si0, st);
                sr1 += __shfl_xor(sr1, st);
                si1 += __shfl_xor(si1, st);
            }
            if (fr == 0)
                red[wr * 16 + wc * 8 + n * 4 + fs] = make_float4(sr0, si0, sr1, si1);
        }
        __syncthreads();
        if (tid < 16) {
            float4 a = red[tid], b2 = red[16 + tid];
            // chunk index = tileM/64 (= b*NC + c); hp base = tileN/4
            sums[(long)(tileM >> 6) * 256 + (tileN >> 2) + tid] =
                make_float4(a.x + b2.x, a.y + b2.y, a.z + b2.z, a.w + b2.w);
        }
    } else {
        float* o = (float*)out;
#pragma unroll
        for (int n = 0; n < 2; ++n) {
            const int col0 = (int)tileN + wc * 32 + n * 16 + fs * 4;   // multiple of 4
            const float4 dv = *(const float4*)(e0 + col0);
#pragma unroll
            for (int m = 0; m < 2; ++m) {
                const long grow = tileM + wr * 32 + m * 16 + fr;
                const long idx = grow * N + col0;
                float u0, u1, u2, u3;
                if (e1b) {
                    ushort4 ub = *(const ushort4*)(e1b + idx);
                    u0 = bf2f(ub.x); u1 = bf2f(ub.y); u2 = bf2f(ub.z); u3 = bf2f(ub.w);
                } else {
                    float4 uf = *(const float4*)(e1 + idx);
                    u0 = uf.x; u1 = uf.y; u2 = uf.z; u3 = uf.w;
                }
                float4 st;
                st.x = acc[m][n][0] + dv.x * u0;
                st.y = acc[m][n][1] + dv.y * u1;
                st.z = acc[m][n][2] + dv.z * u2;
                st.w = acc[m][n][3] + dv.w * u3;
                *(float4*)(o + idx) = st;                              // 16B line-coalesced
            }
        }
    }
}

// ---------- scan: chunk sums fused into K1; k2b carries, k2ac local scan ----------

// k2b: exclusive scan over NC=64 chunk sums -> carry (float4-per-hp layout)
__global__ __launch_bounds__(256) void k2b_carry(const float4* __restrict__ sums,
                                                 float4* __restrict__ carry,
                                                 const float* __restrict__ nu,
                                                 const float* __restrict__ theta) {
    const int gid = blockIdx.x * 256 + threadIdx.x;   // 8*256
    const int hp = gid & 255;
    const int b = gid >> 8;
    float lre0, lim0, lre1, lim1;
    lam_of(nu, theta, 2 * hp, lre0, lim0);
    lam_of(nu, theta, 2 * hp + 1, lre1, lim1);
    // lam^CL via 6 complex squarings (CL = 64 = 2^6)
    float p0r = lre0, p0i = lim0, p1r = lre1, p1i = lim1;
#pragma unroll
    for (int i = 0; i < 6; ++i) {
        float t0 = p0r * p0r - p0i * p0i; p0i = 2.f * p0r * p0i; p0r = t0;
        float t1 = p1r * p1r - p1i * p1i; p1i = 2.f * p1r * p1i; p1r = t1;
    }
    float c0r = 0.f, c0i = 0.f, c1r = 0.f, c1i = 0.f;
#pragma unroll
    for (int c = 0; c < NC; ++c) {
        long idx = ((long)b * NC + c) * 256 + hp;
        carry[idx] = make_float4(c0r, c0i, c1r, c1i);
        float4 s = sums[idx];
        float t0 = fmaf(p0r, c0r, fmaf(-p0i, c0i, s.x));
        c0i = fmaf(p0r, c0i, fmaf(p0i, c0r, s.y));
        c0r = t0;
        float t1 = fmaf(p1r, c1r, fmaf(-p1i, c1i, s.z));
        c1i = fmaf(p1r, c1i, fmaf(p1i, c1r, s.w));
        c1r = t1;
    }
}

// k2ac: fused local scan (CL=64) starting from carry -> final xs (one R+W pass)
__global__ __launch_bounds__(256) void k2ac_scan(ushort4* __restrict__ xs4,
                                                 const float4* __restrict__ carry,
                                                 const float* __restrict__ nu,
                                                 const float* __restrict__ theta) {
    const int gid = blockIdx.x * 256 + threadIdx.x;   // 8*64*256
    const int hp = gid & 255;
    const int c = (gid >> 8) & (NC - 1);
    const int b = gid >> 14;
    float lre0, lim0, lre1, lim1;
    lam_of(nu, theta, 2 * hp, lre0, lim0);
    lam_of(nu, theta, 2 * hp + 1, lre1, lim1);
    float4 cr = carry[((long)b * NC + c) * 256 + hp];
    float a0r = cr.x, a0i = cr.y, a1r = cr.z, a1i = cr.w;
    long base = ((long)b * T_LEN + (long)c * CL) * 256 + hp;
#pragma unroll 4
    for (int i = 0; i < CL; ++i) {
        ushort4 v = xs4[base + (long)i * 256];
        float u0r = bf2f(v.x), u0i = bf2f(v.y), u1r = bf2f(v.z), u1i = bf2f(v.w);
        float n0r = fmaf(lre0, a0r, fmaf(-lim0, a0i, u0r));
        float n0i = fmaf(lre0, a0i, fmaf(lim0, a0r, u0i));
        float n1r = fmaf(lre1, a1r, fmaf(-lim1, a1i, u1r));
        float n1i = fmaf(lre1, a1i, fmaf(lim1, a1r, u1i));
        a0r = n0r; a0i = n0i; a1r = n1r; a1i = n1i;
        ushort4 o;
        o.x = f2bf(a0r); o.y = f2bf(a0i); o.z = f2bf(a1r); o.w = f2bf(a1i);
        xs4[base + (long)i * 256] = o;
    }
}

extern "C" void kernel_launch(void* const* d_in, const int* in_sizes, int n_in,
                              void* d_out, int out_size, void* d_ws, size_t ws_size,
                              hipStream_t stream) {
    const float* x         = (const float*)d_in[0];
    const float* Bre       = (const float*)d_in[1];
    const float* Bim       = (const float*)d_in[2];
    const float* Cre       = (const float*)d_in[3];
    const float* Cim       = (const float*)d_in[4];
    const float* Dv        = (const float*)d_in[5];
    const float* nu        = (const float*)d_in[6];
    const float* theta     = (const float*)d_in[7];
    const float* gamma_log = (const float*)d_in[8];
    float* y = (float*)d_out;

    // ws layout:
    //   [0, 64MB)      xs (bf16 interleaved re,im)
    //   [64MB, 66MB)   region A: BT1 (0.5MB, dead after K1) -> carry (2MB,
    //                  written by k2b, read by k2ac) -> CT (0.5MB, after k2ac)
    //   [66MB, 68MB)   region B: sums (2MB, NC=64; written by K1, read by k2b)
    //   [68MB, 84MB)   xb (bf16 x) IF ws_size permits, else xb lives in d_out
    const size_t XS_BYTES  = (size_t)ROWS * H_DIM * 4;
    const size_t REG_BYTES = 2u * 1024 * 1024;
    const size_t XB_BYTES  = (size_t)ROWS * N_DIM * 2;
    unsigned short* xs_us = (unsigned short*)d_ws;
    ushort4* xs4   = (ushort4*)d_ws;
    char* regionA  = (char*)d_ws + XS_BYTES;
    char* regionB  = regionA + REG_BYTES;
    unsigned short* BT1 = (unsigned short*)regionA;
    float4*  carry = (float4*)regionA;
    unsigned short* CT  = (unsigned short*)regionA;
    float4*  sums  = (float4*)regionB;

    const bool xb_in_ws = ws_size >= XS_BYTES + 2 * REG_BYTES + XB_BYTES;
    unsigned short* xb = xb_in_ws ? (unsigned short*)(regionB + REG_BYTES)
                                  : (unsigned short*)d_out;

    conv_x<<<ROWS * N_DIM / 4 / 256, 256, 0, stream>>>((const float4*)x, (ushort4*)xb);
    conv_Bt<<<(N_DIM * H_DIM) / 256, 256, 0, stream>>>(Bre, Bim, BT1);

    // K1: xs = gamma * (u @ Bint) + fused CL=64 chunk sums
    //     M=32768 N=1024 K=256   (64x64 tiles, 8192 blocks, high occupancy)
    gemm64<0, 256><<<(ROWS / 64) * (1024 / 64), 256, 0, stream>>>(
        xb, BT1, 1024, gamma_log, nullptr, nullptr, nu, theta, sums, xs_us);

    // scan: k2s fused into K1; exclusive carry scan then fused local scan
    k2b_carry<<<(B_SZ * 256) / 256, 256, 0, stream>>>(sums, carry, nu, theta);
    k2ac_scan<<<(B_SZ * NC * 256) / 256, 256, 0, stream>>>(xs4, carry, nu, theta);

    // CT overwrites regionA (BT1/carry both dead after k2ac)
    conv_Ct<<<(H_DIM * N_DIM) / 256, 256, 0, stream>>>(Cre, Cim, CT);

    // K3: y = Re(xs @ C) + D*u   M=32768 N=256 K=1024   (64x64 tiles, 2048 blocks)
    gemm64<1, 1024><<<(ROWS / 64) * (256 / 64), 256, 0, stream>>>(
        xs_us, CT, 256, Dv, x, xb_in_ws ? xb : nullptr, nullptr, nullptr, nullptr, y);
}